// Round 11
// baseline (452.260 us; speedup 1.0000x reference)
//
#include <hip/hip_runtime.h>

// Problem constants
#define BD      4
#define LSEQ    2048
#define DMODEL  1024
#define HHEADS  16
#define DKK     64
#define DFFN    4096
#define MROWS   (BD*LSEQ)   // 8192
#define QKS     2048        // Q|K fused row stride

typedef float  f32x4  __attribute__((ext_vector_type(4)));
typedef float  f32x16 __attribute__((ext_vector_type(16)));
typedef __bf16 bf16x8 __attribute__((ext_vector_type(8)));
typedef unsigned short u16x8 __attribute__((ext_vector_type(8)));
typedef unsigned int   u32x4 __attribute__((ext_vector_type(4)));

__device__ inline unsigned short f2bf(float x) {
    union { float f; unsigned u; } c; c.f = x;
    unsigned r = c.u + 0x7FFFu + ((c.u >> 16) & 1u);
    return (unsigned short)(r >> 16);
}
__device__ inline float bf2f(unsigned short u) {
    union { unsigned u; float f; } c; c.u = ((unsigned)u) << 16;
    return c.f;
}

// ------- fused casts: 6 weights + x + QKV bias concat, 1 launch -------
__global__ void cast_weights_k(const float* __restrict__ wq, const float* __restrict__ wk,
                               const float* __restrict__ wv, const float* __restrict__ wo,
                               const float* __restrict__ w1, const float* __restrict__ w2,
                               const float* __restrict__ x,
                               unsigned short* __restrict__ dqkv, unsigned short* __restrict__ dwo,
                               unsigned short* __restrict__ dw1, unsigned short* __restrict__ dw2,
                               unsigned short* __restrict__ dx,
                               const float* __restrict__ bq, const float* __restrict__ bk,
                               const float* __restrict__ bv, float* __restrict__ bqkv) {
    if (blockIdx.x < 4) {
        int j = blockIdx.x * 256 + threadIdx.x;
        if (j < 1024) { bqkv[j] = bq[j]; bqkv[1024 + j] = bk[j]; bqkv[2048 + j] = bv[j]; }
    }
    const long M1 = 1024*1024;
    long i = ((long)blockIdx.x * blockDim.x + threadIdx.x) * 4;
    long stride = (long)gridDim.x * blockDim.x * 4;
    for (; i < 20*M1; i += stride) {
        const float* src; unsigned short* dst;
        if      (i <   M1) { src = wq + i;          dst = dqkv + i; }
        else if (i < 2*M1) { src = wk + (i-M1);     dst = dqkv + i; }
        else if (i < 3*M1) { src = wv + (i-2*M1);   dst = dqkv + i; }
        else if (i < 4*M1) { src = wo + (i-3*M1);   dst = dwo + (i-3*M1); }
        else if (i < 8*M1) { src = w1 + (i-4*M1);   dst = dw1 + (i-4*M1); }
        else if (i < 12*M1){ src = w2 + (i-8*M1);   dst = dw2 + (i-8*M1); }
        else               { src = x  + (i-12*M1);  dst = dx  + (i-12*M1); }
        float4 v = *(const float4*)src;
        ushort4 o;
        o.x = f2bf(v.x); o.y = f2bf(v.y); o.z = f2bf(v.z); o.w = f2bf(v.w);
        *(ushort4*)dst = o;
    }
}

// ---------------- mask -> bitmask ----------------
__global__ __launch_bounds__(256) void maskbits_k(const int* __restrict__ m,
                                                  unsigned long long* __restrict__ bits) {
    const long gw = ((long)blockIdx.x * blockDim.x + threadIdx.x) >> 6;
    const int lane = threadIdx.x & 63;
    const int b   = (int)(gw >> 16);
    const int rem = (int)gw & 65535;
    const int q = rem >> 5, kt = rem & 31;
    const int v = m[((size_t)(b*LSEQ + q))*LSEQ + kt*64 + lane];
    const unsigned long long bal = __ballot(v != 0);
    if (lane == 0) bits[((size_t)(b*32 + kt))*LSEQ + q] = bal;
}

// ---------------- split-K reduce: out = rb + b2 + P0 + P1 ----------------
__global__ void reduce2_k(const unsigned short* __restrict__ p0,
                          const unsigned short* __restrict__ p1,
                          const float* __restrict__ rb,
                          const float* __restrict__ b2,
                          float* __restrict__ out) {
    long i = ((long)blockIdx.x * blockDim.x + threadIdx.x) * 4;
    long stride = (long)gridDim.x * blockDim.x * 4;
    for (; i < (long)MROWS*DMODEL; i += stride) {
        ushort4 a = *(const ushort4*)(p0 + i);
        ushort4 b = *(const ushort4*)(p1 + i);
        float4 r  = *(const float4*)(rb + i);
        float4 bias = *(const float4*)(b2 + (int)(i & (DMODEL-1)));
        float4 o;
        o.x = r.x + bias.x + bf2f(a.x) + bf2f(b.x);
        o.y = r.y + bias.y + bf2f(a.y) + bf2f(b.y);
        o.z = r.z + bias.z + bf2f(a.z) + bf2f(b.z);
        o.w = r.w + bias.w + bf2f(a.w) + bf2f(b.w);
        *(float4*)(out + i) = o;
    }
}

// ---------------- async global->LDS 16B ----------------
__device__ inline void gload16(const void* g, void* l) {
    __builtin_amdgcn_global_load_lds(
        (const __attribute__((address_space(1))) void*)g,
        (__attribute__((address_space(3))) void*)l, 16, 0, 0);
}

#define BAR() { __builtin_amdgcn_sched_barrier(0); __builtin_amdgcn_s_barrier(); __builtin_amdgcn_sched_barrier(0); }

// =================== 8-phase 256x256 NT GEMM (bf16) ===================
// MODE 1: bf16 + ReLU. MODE 2: f32 + residual. MODE 3: fused QKV epilogue.
// MODE 4: split-K=2 partial (bf16, no bias; kh from bid&1, P0/P1 via Cout/vt).
#define STAGE(XSEL, XPTR, h, tau, s)                                              \
  { const unsigned short* gs0 = (XPTR) + (size_t)((h)*128 + wid*8 + srow) * K + (tau)*64 + schk*8; \
    gload16(gs0, (void*)&sm[(s)][(XSEL)][(((h)*128 + wid*8)*64)]);                 \
    gload16(gs0 + (size_t)64*K, (void*)&sm[(s)][(XSEL)][(((h)*128 + 64 + wid*8)*64)]); }

#define LDA(dst, s, mi, kk) dst = *(const bf16x8*)(&sm[(s)][0][(wr*128 + (mi)*16 + r0)*64 + ((((kk)*4 + g) ^ (r0 & 7)) << 3)]);
#define LDB(dst, s, nj, kk) dst = *(const bf16x8*)(&sm[(s)][1][(wc*64  + (nj)*16 + r0)*64 + ((((kk)*4 + g) ^ (r0 & 7)) << 3)]);

#define PHASE_MFMA(q)                                                                                   \
    __builtin_amdgcn_s_setprio(1);                                                                      \
    _Pragma("unroll")                                                                                   \
    for (int nj = 0; nj < 4; ++nj) {                                                                    \
        acc[2*(q)][nj]   = __builtin_amdgcn_mfma_f32_16x16x32_bf16(af00, bq[nj][0], acc[2*(q)][nj],   0,0,0); \
        acc[2*(q)][nj]   = __builtin_amdgcn_mfma_f32_16x16x32_bf16(af01, bq[nj][1], acc[2*(q)][nj],   0,0,0); \
        acc[2*(q)+1][nj] = __builtin_amdgcn_mfma_f32_16x16x32_bf16(af10, bq[nj][0], acc[2*(q)+1][nj], 0,0,0); \
        acc[2*(q)+1][nj] = __builtin_amdgcn_mfma_f32_16x16x32_bf16(af11, bq[nj][1], acc[2*(q)+1][nj], 0,0,0); \
    }                                                                                                   \
    __builtin_amdgcn_s_setprio(0);

#define KTILE(s, tau)                                                        \
  {                                                                          \
    const int tp1 = (tau) + 1, tp2 = (tau) + 2;                              \
    bf16x8 bq[4][2];                                                         \
    bf16x8 af00, af01, af10, af11;                                           \
    _Pragma("unroll") for (int nj = 0; nj < 4; ++nj) {                       \
        LDB(bq[nj][0], s, nj, 0); LDB(bq[nj][1], s, nj, 1); }                \
    LDA(af00, s, 0, 0); LDA(af01, s, 0, 1);                                  \
    LDA(af10, s, 1, 0); LDA(af11, s, 1, 1);                                  \
    if (tp1 < NTT) { STAGE(0, Ab, 0, tp1, (s)^1); }                          \
    BAR(); PHASE_MFMA(0); BAR();                                             \
    LDA(af00, s, 2, 0); LDA(af01, s, 2, 1);                                  \
    LDA(af10, s, 3, 0); LDA(af11, s, 3, 1);                                  \
    if (tp1 < NTT) { STAGE(0, Ab, 1, tp1, (s)^1); }                          \
    if (tp2 < NTT) { STAGE(1, Bb, 0, tp2, (s)); }                            \
    BAR(); PHASE_MFMA(1); BAR();                                             \
    LDA(af00, s, 4, 0); LDA(af01, s, 4, 1);                                  \
    LDA(af10, s, 5, 0); LDA(af11, s, 5, 1);                                  \
    if (tp2 < NTT) { STAGE(1, Bb, 1, tp2, (s)); }                            \
    BAR(); PHASE_MFMA(2); BAR();                                             \
    LDA(af00, s, 6, 0); LDA(af01, s, 6, 1);                                  \
    LDA(af10, s, 7, 0); LDA(af11, s, 7, 1);                                  \
    if (tp2 < NTT)      { asm volatile("s_waitcnt vmcnt(4)" ::: "memory"); } \
    else if (tp1 < NTT) { asm volatile("s_waitcnt vmcnt(0)" ::: "memory"); } \
    BAR(); PHASE_MFMA(3); BAR();                                             \
  }

template<int MODE, int NTT>
__global__ __launch_bounds__(512, 1) void gemm8(const unsigned short* __restrict__ A,
                                                const unsigned short* __restrict__ B,
                                                const float* __restrict__ bias,
                                                const float* __restrict__ resid,
                                                void* __restrict__ Cout,
                                                unsigned short* __restrict__ vt,
                                                int M, int N, int K, float scaleQ)
{
    __shared__ unsigned short sm[2][2][256*64];
    const int t   = threadIdx.x;
    const int wid = t >> 6, lane = t & 63;
    const int wr  = wid >> 2, wc = wid & 3;
    const int r0  = lane & 15, g = lane >> 4;

    const int nwg = gridDim.x;
    const int bid = (blockIdx.x & 7) * (nwg >> 3) + (blockIdx.x >> 3);

    int bm, bn, koff = 0;
    unsigned short* Pout = (unsigned short*)Cout;
    if (MODE == 4) {
        const int tile = bid >> 1, kh = bid & 1;
        const int ntn = N >> 8;
        bm = (tile / ntn) << 8; bn = (tile % ntn) << 8;
        koff = kh * (K >> 1);
        if (kh) Pout = vt;
    } else {
        const int ntn = N >> 8;
        bm = (bid / ntn) << 8; bn = (bid % ntn) << 8;
    }

    const int srow = lane >> 3;
    const int schk = (lane & 7) ^ srow;
    const unsigned short* Ab = A + (size_t)bm * K + koff;
    const unsigned short* Bb = B + (size_t)bn * K + koff;

    f32x4 acc[8][4] = {};

    STAGE(1, Bb, 0, 0, 0); STAGE(1, Bb, 1, 0, 0);
    STAGE(0, Ab, 0, 0, 0); STAGE(0, Ab, 1, 0, 0);
    STAGE(1, Bb, 0, 1, 1); STAGE(1, Bb, 1, 1, 1);
    asm volatile("s_waitcnt vmcnt(4)" ::: "memory");
    BAR();

#pragma unroll 1
    for (int i2 = 0; i2 < NTT/2; ++i2) {
        const int tau = 2*i2;
        KTILE(0, tau);
        KTILE(1, tau+1);
    }

#pragma unroll
    for (int mi = 0; mi < 8; ++mi) {
        const int row0 = bm + wr*128 + mi*16 + g*4;
#pragma unroll
        for (int nj = 0; nj < 4; ++nj) {
            const int col = bn + wc*64 + nj*16 + r0;
            const float bcol = (MODE == 4) ? 0.f : bias[col];
            if (MODE == 1) {
#pragma unroll
                for (int rr = 0; rr < 4; ++rr) {
                    float c = fmaxf(acc[mi][nj][rr] + bcol, 0.f);
                    ((unsigned short*)Cout)[(size_t)(row0 + rr) * N + col] = f2bf(c);
                }
            } else if (MODE == 2) {
#pragma unroll
                for (int rr = 0; rr < 4; ++rr) {
                    const size_t idx = (size_t)(row0 + rr) * N + col;
                    ((float*)Cout)[idx] = acc[mi][nj][rr] + bcol + resid[idx];
                }
            } else if (MODE == 4) {
#pragma unroll
                for (int rr = 0; rr < 4; ++rr)
                    Pout[(size_t)(row0 + rr) * N + col] = f2bf(acc[mi][nj][rr]);
            } else if (MODE == 3) {
                if (col < 2048) {
                    const float sc = (col < 1024) ? scaleQ : 1.0f;
#pragma unroll
                    for (int rr = 0; rr < 4; ++rr)
                        ((unsigned short*)Cout)[(size_t)(row0 + rr) * QKS + col] =
                            f2bf((acc[mi][nj][rr] + bcol) * sc);
                } else {
                    const int vcol = col - 2048;
                    const int b = row0 >> 11, tok = row0 & 2047;
                    ushort4 h4;
                    h4.x = f2bf(acc[mi][nj][0] + bcol);
                    h4.y = f2bf(acc[mi][nj][1] + bcol);
                    h4.z = f2bf(acc[mi][nj][2] + bcol);
                    h4.w = f2bf(acc[mi][nj][3] + bcol);
                    *(ushort4*)&vt[((size_t)(b*1024 + vcol))*LSEQ + tok] = h4;
                }
            }
        }
    }
}

// =================== 2-phase 256x128 NT GEMM (WO) ===================
#define STAGEA2(h, tau, s)                                                        \
  { const unsigned short* gs0 = Ab + (size_t)((h)*128 + wid*8 + srow) * K + (tau)*64 + schk*8; \
    gload16(gs0, (void*)&smA[(s)][(((h)*128 + wid*8)*64)]);                        \
    gload16(gs0 + (size_t)64*K, (void*)&smA[(s)][(((h)*128 + 64 + wid*8)*64)]); }

#define STAGEB2(tau, s)                                                           \
  { const unsigned short* gs0 = Bb + (size_t)(wid*8 + srow) * K + (tau)*64 + schk*8; \
    gload16(gs0, (void*)&smB[(s)][((wid*8)*64)]);                                  \
    gload16(gs0 + (size_t)64*K, (void*)&smB[(s)][((64 + wid*8)*64)]); }

#define LDA2(dst, s, mi, kk) dst = *(const bf16x8*)(&smA[(s)][(wr*128 + (mi)*16 + r0)*64 + ((((kk)*4 + g) ^ (r0 & 7)) << 3)]);
#define LDB2(dst, s, nj, kk) dst = *(const bf16x8*)(&smB[(s)][(wc*32  + (nj)*16 + r0)*64 + ((((kk)*4 + g) ^ (r0 & 7)) << 3)]);

#define PHASE_MFMA2X(q0)                                                                                \
    __builtin_amdgcn_s_setprio(1);                                                                      \
    _Pragma("unroll")                                                                                   \
    for (int mm = 0; mm < 4; ++mm) {                                                                    \
        acc[(q0)+mm][0] = __builtin_amdgcn_mfma_f32_16x16x32_bf16(aa[2*mm],   bq[0][0], acc[(q0)+mm][0], 0,0,0); \
        acc[(q0)+mm][0] = __builtin_amdgcn_mfma_f32_16x16x32_bf16(aa[2*mm+1], bq[0][1], acc[(q0)+mm][0], 0,0,0); \
        acc[(q0)+mm][1] = __builtin_amdgcn_mfma_f32_16x16x32_bf16(aa[2*mm],   bq[1][0], acc[(q0)+mm][1], 0,0,0); \
        acc[(q0)+mm][1] = __builtin_amdgcn_mfma_f32_16x16x32_bf16(aa[2*mm+1], bq[1][1], acc[(q0)+mm][1], 0,0,0); \
    }                                                                                                   \
    __builtin_amdgcn_s_setprio(0);

#define KTILE2(s, tau)                                                       \
  {                                                                          \
    const int tp1 = (tau) + 1, tp2 = (tau) + 2;                              \
    bf16x8 bq[2][2];                                                         \
    bf16x8 aa[8];                                                            \
    LDB2(bq[0][0], s, 0, 0); LDB2(bq[0][1], s, 0, 1);                        \
    LDB2(bq[1][0], s, 1, 0); LDB2(bq[1][1], s, 1, 1);                        \
    LDA2(aa[0], s, 0, 0); LDA2(aa[1], s, 0, 1);                              \
    LDA2(aa[2], s, 1, 0); LDA2(aa[3], s, 1, 1);                              \
    LDA2(aa[4], s, 2, 0); LDA2(aa[5], s, 2, 1);                              \
    LDA2(aa[6], s, 3, 0); LDA2(aa[7], s, 3, 1);                              \
    if (tp1 < NTT) { STAGEA2(0, tp1, (s)^1); }                               \
    BAR(); PHASE_MFMA2X(0); BAR();                                           \
    LDA2(aa[0], s, 4, 0); LDA2(aa[1], s, 4, 1);                              \
    LDA2(aa[2], s, 5, 0); LDA2(aa[3], s, 5, 1);                              \
    LDA2(aa[4], s, 6, 0); LDA2(aa[5], s, 6, 1);                              \
    LDA2(aa[6], s, 7, 0); LDA2(aa[7], s, 7, 1);                              \
    if (tp1 < NTT) { STAGEA2(1, tp1, (s)^1); }                               \
    if (tp2 < NTT) { STAGEB2(tp2, (s)); }                                    \
    if (tp2 < NTT)      { asm volatile("s_waitcnt vmcnt(2)" ::: "memory"); } \
    else if (tp1 < NTT) { asm volatile("s_waitcnt vmcnt(0)" ::: "memory"); } \
    BAR(); PHASE_MFMA2X(4); BAR();                                           \
  }

template<int MODE, int NTT>
__global__ __launch_bounds__(512, 1) void gemm8n(const unsigned short* __restrict__ A,
                                                 const unsigned short* __restrict__ B,
                                                 const float* __restrict__ bias,
                                                 const float* __restrict__ resid,
                                                 void* __restrict__ Cout,
                                                 int M, int N, int K)
{
    __shared__ unsigned short smA[2][256*64];   // 64 KiB
    __shared__ unsigned short smB[2][128*64];   // 32 KiB
    const int t   = threadIdx.x;
    const int wid = t >> 6, lane = t & 63;
    const int wr  = wid >> 2, wc = wid & 3;
    const int r0  = lane & 15, g = lane >> 4;

    const int nwg = gridDim.x;
    const int bid = (blockIdx.x & 7) * (nwg >> 3) + (blockIdx.x >> 3);
    const int ntn = N >> 7;
    const int bm  = (bid / ntn) << 8, bn = (bid % ntn) << 7;

    const int srow = lane >> 3;
    const int schk = (lane & 7) ^ srow;
    const unsigned short* Ab = A + (size_t)bm * K;
    const unsigned short* Bb = B + (size_t)bn * K;

    f32x4 acc[8][2] = {};

    STAGEB2(0, 0);
    STAGEA2(0, 0, 0); STAGEA2(1, 0, 0);
    STAGEB2(1, 1);
    asm volatile("s_waitcnt vmcnt(2)" ::: "memory");
    BAR();

#pragma unroll 1
    for (int i2 = 0; i2 < NTT/2; ++i2) {
        const int tau = 2*i2;
        KTILE2(0, tau);
        KTILE2(1, tau+1);
    }

#pragma unroll
    for (int mi = 0; mi < 8; ++mi) {
        const int row0 = bm + wr*128 + mi*16 + g*4;
#pragma unroll
        for (int nj = 0; nj < 2; ++nj) {
            const int col = bn + wc*32 + nj*16 + r0;
            const float bcol = bias[col];
#pragma unroll
            for (int rr = 0; rr < 4; ++rr) {
                const int row = row0 + rr;
                if (MODE == 2) {
                    float c = acc[mi][nj][rr] + bcol;
                    ((float*)Cout)[(size_t)row * N + col] = c + resid[(size_t)row * N + col];
                }
            }
        }
    }
}

// ---------------- fused flash attention ----------------
// R8 structure + zero-C trick: first QK^T MFMA of each tile takes a
// never-written zero f32x16 as the C operand (kills 32 v_mov/lane/tile).
#define MFILL   (-47272.79f)    /* -32767 * log2(e) */
#define DEFTHR  (11.5415603f)   /* 8 * log2(e) */
__global__ __launch_bounds__(256, 3) void attn_k(
    const unsigned short* __restrict__ QK,
    const unsigned short* __restrict__ VT,
    const unsigned long long* __restrict__ MBits,
    unsigned short* __restrict__ Z)
{
    __shared__ unsigned short Ks[2][64*64];   // 16 KB
    __shared__ unsigned short Vs[2][64*64];   // 16 KB
    __shared__ float Sc[4*32];

    const int t    = threadIdx.x;
    const int w    = t >> 6, lane = t & 63;
    const int q31  = lane & 31, hi = lane >> 5;

    const int bid = blockIdx.x;
    const int sw  = (bid & 7) * 128 + (bid >> 3);
    const int qt  = sw & 15, h = (sw >> 4) & 15, b = sw >> 8;
    const int qw  = qt * 128 + w * 32;

    const unsigned short* Qg = QK + ((size_t)(b*LSEQ + qw + q31))*QKS + h*DKK + hi*8;
    bf16x8 qf[4];
#pragma unroll
    for (int ds = 0; ds < 4; ++ds)
        qf[ds] = *(const bf16x8*)(Qg + ds*16);

    const int srow = w*8 + (lane>>3);
    const int schk = (lane & 7) ^ (srow & 7);
    const unsigned short* kP = QK + ((size_t)(b*LSEQ))*QKS + 1024 + h*DKK
                                  + (size_t)srow*QKS + schk*8;
    const unsigned short* vP = VT + ((size_t)(b*1024 + h*DKK))*LSEQ
                                  + (size_t)srow*LSEQ + schk*8;
    const unsigned long long* mP = MBits + ((size_t)(b*32))*LSEQ + (qw + q31);

    float m_r = MFILL, l_r = 0.f;
    f32x16 z0, z1, zc;
#pragma unroll
    for (int r = 0; r < 16; ++r) { z0[r] = 0.f; z1[r] = 0.f; zc[r] = 0.f; }
    // keep zc live & unmodified (zero C-operand for first MFMA of each tile)
    asm volatile("" : "+v"(zc));

    gload16(kP,           &Ks[0][w*512]);
    gload16(kP + 32*QKS,  &Ks[0][w*512] + 2048);
    gload16(vP,           &Vs[0][w*512]);
    gload16(vP + 32*LSEQ, &Vs[0][w*512] + 2048);
    unsigned long long mw = *mP;
    kP += 64*QKS; vP += 64; mP += LSEQ;

    for (int kt = 0; kt < LSEQ/64; ++kt) {
        const int cur = kt & 1;
        __syncthreads();

        gload16(kP,           &Ks[cur^1][w*512]);
        gload16(kP + 32*QKS,  &Ks[cur^1][w*512] + 2048);
        gload16(vP,           &Vs[cur^1][w*512]);
        gload16(vP + 32*LSEQ, &Vs[cur^1][w*512] + 2048);
        const unsigned long long mwn = (kt < LSEQ/64 - 1) ? *mP : mw;
        kP += 64*QKS; vP += 64; mP += LSEQ;

        const unsigned long long sh = mw >> (hi*4);
        const unsigned md0 = (unsigned)sh, md1 = (unsigned)(sh >> 32);

        // ---- QK^T (swapped): s = K_tile * Q^T; zc as first C ----
        f32x16 s0, s1;
        __builtin_amdgcn_s_setprio(1);
#pragma unroll
        for (int ds = 0; ds < 4; ++ds) {
            const int slot = ((ds*2 + hi) ^ (q31 & 7)) << 3;
            bf16x8 kf0 = *(const bf16x8*)(&Ks[cur][ q31     *64 + slot]);
            bf16x8 kf1 = *(const bf16x8*)(&Ks[cur][(32+q31)*64 + slot]);
            s0 = __builtin_amdgcn_mfma_f32_32x32x16_bf16(kf0, qf[ds], ds == 0 ? zc : s0, 0, 0, 0);
            s1 = __builtin_amdgcn_mfma_f32_32x32x16_bf16(kf1, qf[ds], ds == 0 ? zc : s1, 0, 0, 0);
        }
        __builtin_amdgcn_s_setprio(0);

        // ---- row max over RAW scores, balanced tree ----
        float a8[16];
#pragma unroll
        for (int r = 0; r < 16; ++r) a8[r] = fmaxf(s0[r], s1[r]);
        {
            float t0 = fmaxf(fmaxf(a8[0],  a8[1]),  a8[2]);
            float t1 = fmaxf(fmaxf(a8[3],  a8[4]),  a8[5]);
            float t2 = fmaxf(fmaxf(a8[6],  a8[7]),  a8[8]);
            float t3 = fmaxf(fmaxf(a8[9],  a8[10]), a8[11]);
            float t4 = fmaxf(fmaxf(a8[12], a8[13]), a8[14]);
            float u0 = fmaxf(fmaxf(t0, t1), t2);
            float u1 = fmaxf(fmaxf(t3, t4), a8[15]);
            float tm = fmaxf(u0, u1);
            float ta = tm, tb = tm;
            asm volatile("v_permlane32_swap_b32 %0, %1" : "+v"(ta), "+v"(tb));
            tm = fmaxf(tm, hi ? ta : tb);

            if (__any(tm > m_r + DEFTHR)) {
                const float nm   = fmaxf(m_r, tm);
                const float corr = exp2f(m_r - nm);
                Sc[w*32 + q31] = corr;
                l_r *= corr;
                m_r  = nm;
#pragma unroll
                for (int r = 0; r < 16; ++r) {
                    const int row = (r & 3) + 8*(r >> 2) + 4*hi;
                    const float cr = Sc[w*32 + row];
                    z0[r] *= cr; z1[r] *= cr;
                }
            }
        }

        // ---- exp (log2 domain) + post-exp mask zeroing ----
#pragma unroll
        for (int r = 0; r < 16; ++r) {
            const int kb = (r & 3) + 8*(r >> 2);
            s0[r] = exp2f(s0[r] - m_r);
            s1[r] = exp2f(s1[r] - m_r);
            if (!((md0 >> kb) & 1)) s0[r] = 0.f;
            if (!((md1 >> kb) & 1)) s1[r] = 0.f;
        }
        // ---- row sum (tree) ----
        float r4[8];
#pragma unroll
        for (int r = 0; r < 8; ++r)
            r4[r] = (s0[2*r] + s0[2*r+1]) + (s1[2*r] + s1[2*r+1]);
        float rs = ((r4[0]+r4[1]) + (r4[2]+r4[3])) + ((r4[4]+r4[5]) + (r4[6]+r4[7]));
        {
            float ra = rs, rb = rs;
            asm volatile("v_permlane32_swap_b32 %0, %1" : "+v"(ra), "+v"(rb));
            rs += hi ? ra : rb;
        }
        l_r += rs;

        // ---- P->bf16 A-frag per ks + PV MFMA ----
        __builtin_amdgcn_s_setprio(1);
#pragma unroll
        for (int half = 0; half < 2; ++half) {
#pragma unroll
            for (int sub = 0; sub < 2; ++sub) {
                const int base = sub*8;
                unsigned wa, wb, wc2, wd;
                float p0 = half ? s1[base+0] : s0[base+0];
                float p1 = half ? s1[base+1] : s0[base+1];
                float p2 = half ? s1[base+2] : s0[base+2];
                float p3 = half ? s1[base+3] : s0[base+3];
                float p4 = half ? s1[base+4] : s0[base+4];
                float p5 = half ? s1[base+5] : s0[base+5];
                float p6 = half ? s1[base+6] : s0[base+6];
                float p7 = half ? s1[base+7] : s0[base+7];
                asm("v_cvt_pk_bf16_f32 %0, %1, %2" : "=v"(wa) : "v"(p0), "v"(p1));
                asm("v_cvt_pk_bf16_f32 %0, %1, %2" : "=v"(wb) : "v"(p4), "v"(p5));
                asm("v_cvt_pk_bf16_f32 %0, %1, %2" : "=v"(wc2) : "v"(p2), "v"(p3));
                asm("v_cvt_pk_bf16_f32 %0, %1, %2" : "=v"(wd) : "v"(p6), "v"(p7));
                asm volatile("v_permlane32_swap_b32 %0, %1" : "+v"(wa), "+v"(wb));
                asm volatile("v_permlane32_swap_b32 %0, %1" : "+v"(wc2), "+v"(wd));
                u32x4 pu; pu[0] = wa; pu[1] = wc2; pu[2] = wb; pu[3] = wd;
                bf16x8 pa = __builtin_bit_cast(bf16x8, pu);
                const int ks = half*2 + sub;
                const int slot = ((ks*2 + hi) ^ (q31 & 7)) << 3;
                bf16x8 vf0 = *(const bf16x8*)(&Vs[cur][ q31     *64 + slot]);
                bf16x8 vf1 = *(const bf16x8*)(&Vs[cur][(32+q31)*64 + slot]);
                z0 = __builtin_amdgcn_mfma_f32_32x32x16_bf16(pa, vf0, z0, 0, 0, 0);
                z1 = __builtin_amdgcn_mfma_f32_32x32x16_bf16(pa, vf1, z1, 0, 0, 0);
            }
        }
        __builtin_amdgcn_s_setprio(0);

        mw = mwn;
    }

    Sc[w*32 + q31] = l_r;
    unsigned short* Zb = Z + ((size_t)(b*LSEQ + qw))*DMODEL + h*DKK + q31;
#pragma unroll
    for (int r = 0; r < 16; ++r) {
        const int row = (r & 3) + 8*(r >> 2) + 4*hi;
        const float rl = 1.0f / Sc[w*32 + row];
        Zb[(size_t)row*DMODEL]      = f2bf(z0[r] * rl);
        Zb[(size_t)row*DMODEL + 32] = f2bf(z1[r] * rl);
    }
}

// ---------------- LayerNorm (f32 in -> bf16 out) ----------------
__global__ __launch_bounds__(256) void ln_k(const float* __restrict__ r,
                                            const float* __restrict__ gam,
                                            const float* __restrict__ bet,
                                            unsigned short* __restrict__ out)
{
    const int row = blockIdx.x;
    const int t = threadIdx.x;
    const float* rp = r + (size_t)row * DMODEL;
    float4 v = *(const float4*)(rp + t*4);
    float s  = v.x + v.y + v.z + v.w;
    float s2 = v.x*v.x + v.y*v.y + v.z*v.z + v.w*v.w;
#pragma unroll
    for (int off = 32; off >= 1; off >>= 1) {
        s  += __shfl_xor(s,  off);
        s2 += __shfl_xor(s2, off);
    }
    __shared__ float red[8];
    const int wv = t >> 6;
    if ((t & 63) == 0) { red[wv] = s; red[4 + wv] = s2; }
    __syncthreads();
    s  = red[0] + red[1] + red[2] + red[3];
    s2 = red[4] + red[5] + red[6] + red[7];
    const float mu   = s  * (1.f/DMODEL);
    const float var  = s2 * (1.f/DMODEL) - mu*mu;
    const float rstd = rsqrtf(var + 1e-5f);
    float4 gv = *(const float4*)(gam + t*4);
    float4 bv = *(const float4*)(bet + t*4);
    ushort4 o;
    o.x = f2bf((v.x - mu)*rstd*gv.x + bv.x);
    o.y = f2bf((v.y - mu)*rstd*gv.y + bv.y);
    o.z = f2bf((v.z - mu)*rstd*gv.z + bv.z);
    o.w = f2bf((v.w - mu)*rstd*gv.w + bv.w);
    *(ushort4*)(out + (size_t)row * DMODEL + t*4) = o;
}

extern "C" void kernel_launch(void* const* d_in, const int* in_sizes, int n_in,
                              void* d_out, int out_size, void* d_ws, size_t ws_size,
                              hipStream_t stream)
{
    const float* x    = (const float*)d_in[0];
    const int*   mask = (const int*)  d_in[1];
    const float* WQ_w = (const float*)d_in[2];
    const float* WQ_b = (const float*)d_in[3];
    const float* WK_w = (const float*)d_in[4];
    const float* WK_b = (const float*)d_in[5];
    const float* WV_w = (const float*)d_in[6];
    const float* WV_b = (const float*)d_in[7];
    const float* WO_w = (const float*)d_in[8];
    const float* WO_b = (const float*)d_in[9];
    const float* ln_g = (const float*)d_in[10];
    const float* ln_b = (const float*)d_in[11];
    const float* W1_w = (const float*)d_in[12];
    const float* W1_b = (const float*)d_in[13];
    const float* W2_w = (const float*)d_in[14];
    const float* W2_b = (const float*)d_in[15];
    float* out = (float*)d_out;

    char* w = (char*)d_ws;
    const size_t MB = 1024*1024;
    unsigned short* qk   = (unsigned short*)(w + 0*MB);    // 32MB  Q|K rowmajor
    unsigned short* vtb  = (unsigned short*)(w + 32*MB);   // 32MB  V^T
    unsigned short* shr  = (unsigned short*)(w + 64*MB);   // 16MB  xb / Zb / hln / P0
    float*          rb   = (float*)         (w + 80*MB);   // 32MB  (bqkv early)
    unsigned short* wqkv = (unsigned short*)(w + 112*MB);  // 6MB   (P1 later)
    unsigned short* wob  = (unsigned short*)(w + 118*MB);  // 2MB
    unsigned short* w1b  = (unsigned short*)(w + 120*MB);  // 8MB
    unsigned short* w2b  = (unsigned short*)(w + 128*MB);  // 8MB
    unsigned long long* mbits = (unsigned long long*)(w + 136*MB); // 2MB -> 138MB
    float* bqkv = (float*)rb;                              // dead before WO writes rb
    unsigned short* xb   = shr;
    unsigned short* Zb   = shr;
    unsigned short* hln  = shr;
    unsigned short* hmid = (unsigned short*)(w + 0*MB);    // qk+vtb dead after attn
    unsigned short* P0   = shr;                            // hln dead after W1
    unsigned short* P1   = wqkv;                           // weights dead after W1

    // fused casts (weights + x + biases) + bitmask
    cast_weights_k<<<2048, 256, 0, stream>>>(WQ_w, WK_w, WV_w, WO_w, W1_w, W2_w, x,
                                             wqkv, wob, w1b, w2b, xb,
                                             WQ_b, WK_b, WV_b, bqkv);
    maskbits_k<<<65536, 256, 0, stream>>>(mask, mbits);

    // fused QKV projection on 8-phase 256x256 (MODE 3: QK rowmajor + V^T)
    gemm8<3, 16><<<dim3(384), dim3(512), 0, stream>>>(xb, wqkv, bqkv, nullptr, qk, vtb,
                                                      MROWS, 3072, DMODEL, 0.18033688f);
    // fused attention
    attn_k<<<dim3(1024), dim3(256), 0, stream>>>(qk, vtb, mbits, Zb);
    // WO projection + residual 1 -> r (f32); 2-phase 256x128, grid 256
    gemm8n<2, 16><<<dim3(256), dim3(512), 0, stream>>>(Zb, wob, WO_b, x, rb,
                                                       MROWS, DMODEL, DMODEL);
    // pre-LN of FFN
    ln_k<<<MROWS, 256, 0, stream>>>(rb, ln_g, ln_b, hln);
    // FFN
    gemm8<1, 16><<<dim3(512), dim3(512), 0, stream>>>(hln, w1b, W1_b, nullptr, hmid, nullptr,
                                                      MROWS, DFFN, DMODEL, 1.0f);
    // W2 split-K=2: 256 blocks (full machine), bf16 partials P0/P1
    gemm8<4, 32><<<dim3(256), dim3(512), 0, stream>>>(hmid, w2b, nullptr, nullptr, P0, P1,
                                                      MROWS, DMODEL, DFFN, 1.0f);
    // final reduce: out = rb + b2 + P0 + P1
    reduce2_k<<<2048, 256, 0, stream>>>(P0, P1, rb, W2_b, out);
}

// Round 12
// 440.713 us; speedup vs baseline: 1.0262x; 1.0262x over previous
//
#include <hip/hip_runtime.h>

// Problem constants
#define BD      4
#define LSEQ    2048
#define DMODEL  1024
#define HHEADS  16
#define DKK     64
#define DFFN    4096
#define MROWS   (BD*LSEQ)   // 8192
#define QKS     2048        // Q|K fused row stride

typedef float  f32x4  __attribute__((ext_vector_type(4)));
typedef float  f32x16 __attribute__((ext_vector_type(16)));
typedef __bf16 bf16x8 __attribute__((ext_vector_type(8)));
typedef unsigned short u16x8 __attribute__((ext_vector_type(8)));
typedef unsigned int   u32x4 __attribute__((ext_vector_type(4)));

__device__ inline unsigned short f2bf(float x) {
    union { float f; unsigned u; } c; c.f = x;
    unsigned r = c.u + 0x7FFFu + ((c.u >> 16) & 1u);
    return (unsigned short)(r >> 16);
}
__device__ inline float bf2f(unsigned short u) {
    union { unsigned u; float f; } c; c.u = ((unsigned)u) << 16;
    return c.f;
}

// ------- fused casts: 6 weights + x + QKV bias concat, 1 launch -------
__global__ void cast_weights_k(const float* __restrict__ wq, const float* __restrict__ wk,
                               const float* __restrict__ wv, const float* __restrict__ wo,
                               const float* __restrict__ w1, const float* __restrict__ w2,
                               const float* __restrict__ x,
                               unsigned short* __restrict__ dqkv, unsigned short* __restrict__ dwo,
                               unsigned short* __restrict__ dw1, unsigned short* __restrict__ dw2,
                               unsigned short* __restrict__ dx,
                               const float* __restrict__ bq, const float* __restrict__ bk,
                               const float* __restrict__ bv, float* __restrict__ bqkv) {
    if (blockIdx.x < 4) {
        int j = blockIdx.x * 256 + threadIdx.x;
        if (j < 1024) { bqkv[j] = bq[j]; bqkv[1024 + j] = bk[j]; bqkv[2048 + j] = bv[j]; }
    }
    const long M1 = 1024*1024;
    long i = ((long)blockIdx.x * blockDim.x + threadIdx.x) * 4;
    long stride = (long)gridDim.x * blockDim.x * 4;
    for (; i < 20*M1; i += stride) {
        const float* src; unsigned short* dst;
        if      (i <   M1) { src = wq + i;          dst = dqkv + i; }
        else if (i < 2*M1) { src = wk + (i-M1);     dst = dqkv + i; }
        else if (i < 3*M1) { src = wv + (i-2*M1);   dst = dqkv + i; }
        else if (i < 4*M1) { src = wo + (i-3*M1);   dst = dwo + (i-3*M1); }
        else if (i < 8*M1) { src = w1 + (i-4*M1);   dst = dw1 + (i-4*M1); }
        else if (i < 12*M1){ src = w2 + (i-8*M1);   dst = dw2 + (i-8*M1); }
        else               { src = x  + (i-12*M1);  dst = dx  + (i-12*M1); }
        float4 v = *(const float4*)src;
        ushort4 o;
        o.x = f2bf(v.x); o.y = f2bf(v.y); o.z = f2bf(v.z); o.w = f2bf(v.w);
        *(ushort4*)dst = o;
    }
}

// ---------------- mask -> bitmask ----------------
__global__ __launch_bounds__(256) void maskbits_k(const int* __restrict__ m,
                                                  unsigned long long* __restrict__ bits) {
    const long gw = ((long)blockIdx.x * blockDim.x + threadIdx.x) >> 6;
    const int lane = threadIdx.x & 63;
    const int b   = (int)(gw >> 16);
    const int rem = (int)gw & 65535;
    const int q = rem >> 5, kt = rem & 31;
    const int v = m[((size_t)(b*LSEQ + q))*LSEQ + kt*64 + lane];
    const unsigned long long bal = __ballot(v != 0);
    if (lane == 0) bits[((size_t)(b*32 + kt))*LSEQ + q] = bal;
}

// ---------------- split-K reduce: out = rb + b2 + P0 + P1 ----------------
__global__ void reduce2_k(const unsigned short* __restrict__ p0,
                          const unsigned short* __restrict__ p1,
                          const float* __restrict__ rb,
                          const float* __restrict__ b2,
                          float* __restrict__ out) {
    long i = ((long)blockIdx.x * blockDim.x + threadIdx.x) * 4;
    long stride = (long)gridDim.x * blockDim.x * 4;
    for (; i < (long)MROWS*DMODEL; i += stride) {
        ushort4 a = *(const ushort4*)(p0 + i);
        ushort4 b = *(const ushort4*)(p1 + i);
        float4 r  = *(const float4*)(rb + i);
        float4 bias = *(const float4*)(b2 + (int)(i & (DMODEL-1)));
        float4 o;
        o.x = r.x + bias.x + bf2f(a.x) + bf2f(b.x);
        o.y = r.y + bias.y + bf2f(a.y) + bf2f(b.y);
        o.z = r.z + bias.z + bf2f(a.z) + bf2f(b.z);
        o.w = r.w + bias.w + bf2f(a.w) + bf2f(b.w);
        *(float4*)(out + i) = o;
    }
}

// ---------------- async global->LDS 16B ----------------
__device__ inline void gload16(const void* g, void* l) {
    __builtin_amdgcn_global_load_lds(
        (const __attribute__((address_space(1))) void*)g,
        (__attribute__((address_space(3))) void*)l, 16, 0, 0);
}

#define BAR() { __builtin_amdgcn_sched_barrier(0); __builtin_amdgcn_s_barrier(); __builtin_amdgcn_sched_barrier(0); }

// =================== 8-phase 256x256 NT GEMM (bf16) ===================
// MODE 1: bf16 + ReLU. MODE 2: f32 + residual. MODE 3: fused QKV epilogue.
// MODE 4: split-K=2 partial (bf16, no bias; kh from bid&1, P0/P1 via Cout/vt).
#define STAGE(XSEL, XPTR, h, tau, s)                                              \
  { const unsigned short* gs0 = (XPTR) + (size_t)((h)*128 + wid*8 + srow) * K + (tau)*64 + schk*8; \
    gload16(gs0, (void*)&sm[(s)][(XSEL)][(((h)*128 + wid*8)*64)]);                 \
    gload16(gs0 + (size_t)64*K, (void*)&sm[(s)][(XSEL)][(((h)*128 + 64 + wid*8)*64)]); }

#define LDA(dst, s, mi, kk) dst = *(const bf16x8*)(&sm[(s)][0][(wr*128 + (mi)*16 + r0)*64 + ((((kk)*4 + g) ^ (r0 & 7)) << 3)]);
#define LDB(dst, s, nj, kk) dst = *(const bf16x8*)(&sm[(s)][1][(wc*64  + (nj)*16 + r0)*64 + ((((kk)*4 + g) ^ (r0 & 7)) << 3)]);

#define PHASE_MFMA(q)                                                                                   \
    __builtin_amdgcn_s_setprio(1);                                                                      \
    _Pragma("unroll")                                                                                   \
    for (int nj = 0; nj < 4; ++nj) {                                                                    \
        acc[2*(q)][nj]   = __builtin_amdgcn_mfma_f32_16x16x32_bf16(af00, bq[nj][0], acc[2*(q)][nj],   0,0,0); \
        acc[2*(q)][nj]   = __builtin_amdgcn_mfma_f32_16x16x32_bf16(af01, bq[nj][1], acc[2*(q)][nj],   0,0,0); \
        acc[2*(q)+1][nj] = __builtin_amdgcn_mfma_f32_16x16x32_bf16(af10, bq[nj][0], acc[2*(q)+1][nj], 0,0,0); \
        acc[2*(q)+1][nj] = __builtin_amdgcn_mfma_f32_16x16x32_bf16(af11, bq[nj][1], acc[2*(q)+1][nj], 0,0,0); \
    }                                                                                                   \
    __builtin_amdgcn_s_setprio(0);

#define KTILE(s, tau)                                                        \
  {                                                                          \
    const int tp1 = (tau) + 1, tp2 = (tau) + 2;                              \
    bf16x8 bq[4][2];                                                         \
    bf16x8 af00, af01, af10, af11;                                           \
    _Pragma("unroll") for (int nj = 0; nj < 4; ++nj) {                       \
        LDB(bq[nj][0], s, nj, 0); LDB(bq[nj][1], s, nj, 1); }                \
    LDA(af00, s, 0, 0); LDA(af01, s, 0, 1);                                  \
    LDA(af10, s, 1, 0); LDA(af11, s, 1, 1);                                  \
    if (tp1 < NTT) { STAGE(0, Ab, 0, tp1, (s)^1); }                          \
    BAR(); PHASE_MFMA(0); BAR();                                             \
    LDA(af00, s, 2, 0); LDA(af01, s, 2, 1);                                  \
    LDA(af10, s, 3, 0); LDA(af11, s, 3, 1);                                  \
    if (tp1 < NTT) { STAGE(0, Ab, 1, tp1, (s)^1); }                          \
    if (tp2 < NTT) { STAGE(1, Bb, 0, tp2, (s)); }                            \
    BAR(); PHASE_MFMA(1); BAR();                                             \
    LDA(af00, s, 4, 0); LDA(af01, s, 4, 1);                                  \
    LDA(af10, s, 5, 0); LDA(af11, s, 5, 1);                                  \
    if (tp2 < NTT) { STAGE(1, Bb, 1, tp2, (s)); }                            \
    BAR(); PHASE_MFMA(2); BAR();                                             \
    LDA(af00, s, 6, 0); LDA(af01, s, 6, 1);                                  \
    LDA(af10, s, 7, 0); LDA(af11, s, 7, 1);                                  \
    if (tp2 < NTT)      { asm volatile("s_waitcnt vmcnt(4)" ::: "memory"); } \
    else if (tp1 < NTT) { asm volatile("s_waitcnt vmcnt(0)" ::: "memory"); } \
    BAR(); PHASE_MFMA(3); BAR();                                             \
  }

template<int MODE, int NTT>
__global__ __launch_bounds__(512, 1) void gemm8(const unsigned short* __restrict__ A,
                                                const unsigned short* __restrict__ B,
                                                const float* __restrict__ bias,
                                                const float* __restrict__ resid,
                                                void* __restrict__ Cout,
                                                unsigned short* __restrict__ vt,
                                                int M, int N, int K, float scaleQ)
{
    __shared__ unsigned short sm[2][2][256*64];
    const int t   = threadIdx.x;
    const int wid = t >> 6, lane = t & 63;
    const int wr  = wid >> 2, wc = wid & 3;
    const int r0  = lane & 15, g = lane >> 4;

    const int nwg = gridDim.x;
    const int bid = (blockIdx.x & 7) * (nwg >> 3) + (blockIdx.x >> 3);

    int bm, bn, koff = 0;
    unsigned short* Pout = (unsigned short*)Cout;
    if (MODE == 4) {
        const int tile = bid >> 1, kh = bid & 1;
        const int ntn = N >> 8;
        bm = (tile / ntn) << 8; bn = (tile % ntn) << 8;
        koff = kh * (K >> 1);
        if (kh) Pout = vt;
    } else {
        const int ntn = N >> 8;
        bm = (bid / ntn) << 8; bn = (bid % ntn) << 8;
    }

    const int srow = lane >> 3;
    const int schk = (lane & 7) ^ srow;
    const unsigned short* Ab = A + (size_t)bm * K + koff;
    const unsigned short* Bb = B + (size_t)bn * K + koff;

    f32x4 acc[8][4] = {};

    STAGE(1, Bb, 0, 0, 0); STAGE(1, Bb, 1, 0, 0);
    STAGE(0, Ab, 0, 0, 0); STAGE(0, Ab, 1, 0, 0);
    STAGE(1, Bb, 0, 1, 1); STAGE(1, Bb, 1, 1, 1);
    asm volatile("s_waitcnt vmcnt(4)" ::: "memory");
    BAR();

#pragma unroll 1
    for (int i2 = 0; i2 < NTT/2; ++i2) {
        const int tau = 2*i2;
        KTILE(0, tau);
        KTILE(1, tau+1);
    }

#pragma unroll
    for (int mi = 0; mi < 8; ++mi) {
        const int row0 = bm + wr*128 + mi*16 + g*4;
#pragma unroll
        for (int nj = 0; nj < 4; ++nj) {
            const int col = bn + wc*64 + nj*16 + r0;
            const float bcol = (MODE == 4) ? 0.f : bias[col];
            if (MODE == 1) {
#pragma unroll
                for (int rr = 0; rr < 4; ++rr) {
                    float c = fmaxf(acc[mi][nj][rr] + bcol, 0.f);
                    ((unsigned short*)Cout)[(size_t)(row0 + rr) * N + col] = f2bf(c);
                }
            } else if (MODE == 2) {
#pragma unroll
                for (int rr = 0; rr < 4; ++rr) {
                    const size_t idx = (size_t)(row0 + rr) * N + col;
                    ((float*)Cout)[idx] = acc[mi][nj][rr] + bcol + resid[idx];
                }
            } else if (MODE == 4) {
#pragma unroll
                for (int rr = 0; rr < 4; ++rr)
                    Pout[(size_t)(row0 + rr) * N + col] = f2bf(acc[mi][nj][rr]);
            } else if (MODE == 3) {
                if (col < 2048) {
                    const float sc = (col < 1024) ? scaleQ : 1.0f;
#pragma unroll
                    for (int rr = 0; rr < 4; ++rr)
                        ((unsigned short*)Cout)[(size_t)(row0 + rr) * QKS + col] =
                            f2bf((acc[mi][nj][rr] + bcol) * sc);
                } else {
                    const int vcol = col - 2048;
                    const int b = row0 >> 11, tok = row0 & 2047;
                    ushort4 h4;
                    h4.x = f2bf(acc[mi][nj][0] + bcol);
                    h4.y = f2bf(acc[mi][nj][1] + bcol);
                    h4.z = f2bf(acc[mi][nj][2] + bcol);
                    h4.w = f2bf(acc[mi][nj][3] + bcol);
                    *(ushort4*)&vt[((size_t)(b*1024 + vcol))*LSEQ + tok] = h4;
                }
            }
        }
    }
}

// =================== 2-phase 256x128 NT GEMM (WO) ===================
#define STAGEA2(h, tau, s)                                                        \
  { const unsigned short* gs0 = Ab + (size_t)((h)*128 + wid*8 + srow) * K + (tau)*64 + schk*8; \
    gload16(gs0, (void*)&smA[(s)][(((h)*128 + wid*8)*64)]);                        \
    gload16(gs0 + (size_t)64*K, (void*)&smA[(s)][(((h)*128 + 64 + wid*8)*64)]); }

#define STAGEB2(tau, s)                                                           \
  { const unsigned short* gs0 = Bb + (size_t)(wid*8 + srow) * K + (tau)*64 + schk*8; \
    gload16(gs0, (void*)&smB[(s)][((wid*8)*64)]);                                  \
    gload16(gs0 + (size_t)64*K, (void*)&smB[(s)][((64 + wid*8)*64)]); }

#define LDA2(dst, s, mi, kk) dst = *(const bf16x8*)(&smA[(s)][(wr*128 + (mi)*16 + r0)*64 + ((((kk)*4 + g) ^ (r0 & 7)) << 3)]);
#define LDB2(dst, s, nj, kk) dst = *(const bf16x8*)(&smB[(s)][(wc*32  + (nj)*16 + r0)*64 + ((((kk)*4 + g) ^ (r0 & 7)) << 3)]);

#define PHASE_MFMA2X(q0)                                                                                \
    __builtin_amdgcn_s_setprio(1);                                                                      \
    _Pragma("unroll")                                                                                   \
    for (int mm = 0; mm < 4; ++mm) {                                                                    \
        acc[(q0)+mm][0] = __builtin_amdgcn_mfma_f32_16x16x32_bf16(aa[2*mm],   bq[0][0], acc[(q0)+mm][0], 0,0,0); \
        acc[(q0)+mm][0] = __builtin_amdgcn_mfma_f32_16x16x32_bf16(aa[2*mm+1], bq[0][1], acc[(q0)+mm][0], 0,0,0); \
        acc[(q0)+mm][1] = __builtin_amdgcn_mfma_f32_16x16x32_bf16(aa[2*mm],   bq[1][0], acc[(q0)+mm][1], 0,0,0); \
        acc[(q0)+mm][1] = __builtin_amdgcn_mfma_f32_16x16x32_bf16(aa[2*mm+1], bq[1][1], acc[(q0)+mm][1], 0,0,0); \
    }                                                                                                   \
    __builtin_amdgcn_s_setprio(0);

#define KTILE2(s, tau)                                                       \
  {                                                                          \
    const int tp1 = (tau) + 1, tp2 = (tau) + 2;                              \
    bf16x8 bq[2][2];                                                         \
    bf16x8 aa[8];                                                            \
    LDB2(bq[0][0], s, 0, 0); LDB2(bq[0][1], s, 0, 1);                        \
    LDB2(bq[1][0], s, 1, 0); LDB2(bq[1][1], s, 1, 1);                        \
    LDA2(aa[0], s, 0, 0); LDA2(aa[1], s, 0, 1);                              \
    LDA2(aa[2], s, 1, 0); LDA2(aa[3], s, 1, 1);                              \
    LDA2(aa[4], s, 2, 0); LDA2(aa[5], s, 2, 1);                              \
    LDA2(aa[6], s, 3, 0); LDA2(aa[7], s, 3, 1);                              \
    if (tp1 < NTT) { STAGEA2(0, tp1, (s)^1); }                               \
    BAR(); PHASE_MFMA2X(0); BAR();                                           \
    LDA2(aa[0], s, 4, 0); LDA2(aa[1], s, 4, 1);                              \
    LDA2(aa[2], s, 5, 0); LDA2(aa[3], s, 5, 1);                              \
    LDA2(aa[4], s, 6, 0); LDA2(aa[5], s, 6, 1);                              \
    LDA2(aa[6], s, 7, 0); LDA2(aa[7], s, 7, 1);                              \
    if (tp1 < NTT) { STAGEA2(1, tp1, (s)^1); }                               \
    if (tp2 < NTT) { STAGEB2(tp2, (s)); }                                    \
    if (tp2 < NTT)      { asm volatile("s_waitcnt vmcnt(2)" ::: "memory"); } \
    else if (tp1 < NTT) { asm volatile("s_waitcnt vmcnt(0)" ::: "memory"); } \
    BAR(); PHASE_MFMA2X(4); BAR();                                           \
  }

template<int MODE, int NTT>
__global__ __launch_bounds__(512, 1) void gemm8n(const unsigned short* __restrict__ A,
                                                 const unsigned short* __restrict__ B,
                                                 const float* __restrict__ bias,
                                                 const float* __restrict__ resid,
                                                 void* __restrict__ Cout,
                                                 int M, int N, int K)
{
    __shared__ unsigned short smA[2][256*64];   // 64 KiB
    __shared__ unsigned short smB[2][128*64];   // 32 KiB
    const int t   = threadIdx.x;
    const int wid = t >> 6, lane = t & 63;
    const int wr  = wid >> 2, wc = wid & 3;
    const int r0  = lane & 15, g = lane >> 4;

    const int nwg = gridDim.x;
    const int bid = (blockIdx.x & 7) * (nwg >> 3) + (blockIdx.x >> 3);
    const int ntn = N >> 7;
    const int bm  = (bid / ntn) << 8, bn = (bid % ntn) << 7;

    const int srow = lane >> 3;
    const int schk = (lane & 7) ^ srow;
    const unsigned short* Ab = A + (size_t)bm * K;
    const unsigned short* Bb = B + (size_t)bn * K;

    f32x4 acc[8][2] = {};

    STAGEB2(0, 0);
    STAGEA2(0, 0, 0); STAGEA2(1, 0, 0);
    STAGEB2(1, 1);
    asm volatile("s_waitcnt vmcnt(2)" ::: "memory");
    BAR();

#pragma unroll 1
    for (int i2 = 0; i2 < NTT/2; ++i2) {
        const int tau = 2*i2;
        KTILE2(0, tau);
        KTILE2(1, tau+1);
    }

#pragma unroll
    for (int mi = 0; mi < 8; ++mi) {
        const int row0 = bm + wr*128 + mi*16 + g*4;
#pragma unroll
        for (int nj = 0; nj < 2; ++nj) {
            const int col = bn + wc*32 + nj*16 + r0;
            const float bcol = bias[col];
#pragma unroll
            for (int rr = 0; rr < 4; ++rr) {
                const int row = row0 + rr;
                if (MODE == 2) {
                    float c = acc[mi][nj][rr] + bcol;
                    ((float*)Cout)[(size_t)row * N + col] = c + resid[(size_t)row * N + col];
                }
            }
        }
    }
}

// ---------------- fused flash attention (R10/R8 version, zc trick reverted) --
#define MFILL   (-47272.79f)    /* -32767 * log2(e) */
#define DEFTHR  (11.5415603f)   /* 8 * log2(e) */
__global__ __launch_bounds__(256, 3) void attn_k(
    const unsigned short* __restrict__ QK,
    const unsigned short* __restrict__ VT,
    const unsigned long long* __restrict__ MBits,
    unsigned short* __restrict__ Z)
{
    __shared__ unsigned short Ks[2][64*64];   // 16 KB
    __shared__ unsigned short Vs[2][64*64];   // 16 KB
    __shared__ float Sc[4*32];

    const int t    = threadIdx.x;
    const int w    = t >> 6, lane = t & 63;
    const int q31  = lane & 31, hi = lane >> 5;

    const int bid = blockIdx.x;
    const int sw  = (bid & 7) * 128 + (bid >> 3);
    const int qt  = sw & 15, h = (sw >> 4) & 15, b = sw >> 8;
    const int qw  = qt * 128 + w * 32;

    const unsigned short* Qg = QK + ((size_t)(b*LSEQ + qw + q31))*QKS + h*DKK + hi*8;
    bf16x8 qf[4];
#pragma unroll
    for (int ds = 0; ds < 4; ++ds)
        qf[ds] = *(const bf16x8*)(Qg + ds*16);

    const int srow = w*8 + (lane>>3);
    const int schk = (lane & 7) ^ (srow & 7);
    const unsigned short* kP = QK + ((size_t)(b*LSEQ))*QKS + 1024 + h*DKK
                                  + (size_t)srow*QKS + schk*8;
    const unsigned short* vP = VT + ((size_t)(b*1024 + h*DKK))*LSEQ
                                  + (size_t)srow*LSEQ + schk*8;
    const unsigned long long* mP = MBits + ((size_t)(b*32))*LSEQ + (qw + q31);

    float m_r = MFILL, l_r = 0.f;
    f32x16 z0, z1;
#pragma unroll
    for (int r = 0; r < 16; ++r) { z0[r] = 0.f; z1[r] = 0.f; }

    gload16(kP,           &Ks[0][w*512]);
    gload16(kP + 32*QKS,  &Ks[0][w*512] + 2048);
    gload16(vP,           &Vs[0][w*512]);
    gload16(vP + 32*LSEQ, &Vs[0][w*512] + 2048);
    unsigned long long mw = *mP;
    kP += 64*QKS; vP += 64; mP += LSEQ;

    for (int kt = 0; kt < LSEQ/64; ++kt) {
        const int cur = kt & 1;
        __syncthreads();

        gload16(kP,           &Ks[cur^1][w*512]);
        gload16(kP + 32*QKS,  &Ks[cur^1][w*512] + 2048);
        gload16(vP,           &Vs[cur^1][w*512]);
        gload16(vP + 32*LSEQ, &Vs[cur^1][w*512] + 2048);
        const unsigned long long mwn = (kt < LSEQ/64 - 1) ? *mP : mw;
        kP += 64*QKS; vP += 64; mP += LSEQ;

        const unsigned long long sh = mw >> (hi*4);
        const unsigned md0 = (unsigned)sh, md1 = (unsigned)(sh >> 32);

        f32x16 s0, s1;
#pragma unroll
        for (int r = 0; r < 16; ++r) { s0[r] = 0.f; s1[r] = 0.f; }
        __builtin_amdgcn_s_setprio(1);
#pragma unroll
        for (int ds = 0; ds < 4; ++ds) {
            const int slot = ((ds*2 + hi) ^ (q31 & 7)) << 3;
            bf16x8 kf0 = *(const bf16x8*)(&Ks[cur][ q31     *64 + slot]);
            bf16x8 kf1 = *(const bf16x8*)(&Ks[cur][(32+q31)*64 + slot]);
            s0 = __builtin_amdgcn_mfma_f32_32x32x16_bf16(kf0, qf[ds], s0, 0, 0, 0);
            s1 = __builtin_amdgcn_mfma_f32_32x32x16_bf16(kf1, qf[ds], s1, 0, 0, 0);
        }
        __builtin_amdgcn_s_setprio(0);

        float a8[16];
#pragma unroll
        for (int r = 0; r < 16; ++r) a8[r] = fmaxf(s0[r], s1[r]);
        {
            float t0 = fmaxf(fmaxf(a8[0],  a8[1]),  a8[2]);
            float t1 = fmaxf(fmaxf(a8[3],  a8[4]),  a8[5]);
            float t2 = fmaxf(fmaxf(a8[6],  a8[7]),  a8[8]);
            float t3 = fmaxf(fmaxf(a8[9],  a8[10]), a8[11]);
            float t4 = fmaxf(fmaxf(a8[12], a8[13]), a8[14]);
            float u0 = fmaxf(fmaxf(t0, t1), t2);
            float u1 = fmaxf(fmaxf(t3, t4), a8[15]);
            float tm = fmaxf(u0, u1);
            float ta = tm, tb = tm;
            asm volatile("v_permlane32_swap_b32 %0, %1" : "+v"(ta), "+v"(tb));
            tm = fmaxf(tm, hi ? ta : tb);

            if (__any(tm > m_r + DEFTHR)) {
                const float nm   = fmaxf(m_r, tm);
                const float corr = exp2f(m_r - nm);
                Sc[w*32 + q31] = corr;
                l_r *= corr;
                m_r  = nm;
#pragma unroll
                for (int r = 0; r < 16; ++r) {
                    const int row = (r & 3) + 8*(r >> 2) + 4*hi;
                    const float cr = Sc[w*32 + row];
                    z0[r] *= cr; z1[r] *= cr;
                }
            }
        }

#pragma unroll
        for (int r = 0; r < 16; ++r) {
            const int kb = (r & 3) + 8*(r >> 2);
            s0[r] = exp2f(s0[r] - m_r);
            s1[r] = exp2f(s1[r] - m_r);
            if (!((md0 >> kb) & 1)) s0[r] = 0.f;
            if (!((md1 >> kb) & 1)) s1[r] = 0.f;
        }
        float r4[8];
#pragma unroll
        for (int r = 0; r < 8; ++r)
            r4[r] = (s0[2*r] + s0[2*r+1]) + (s1[2*r] + s1[2*r+1]);
        float rs = ((r4[0]+r4[1]) + (r4[2]+r4[3])) + ((r4[4]+r4[5]) + (r4[6]+r4[7]));
        {
            float ra = rs, rb = rs;
            asm volatile("v_permlane32_swap_b32 %0, %1" : "+v"(ra), "+v"(rb));
            rs += hi ? ra : rb;
        }
        l_r += rs;

        __builtin_amdgcn_s_setprio(1);
#pragma unroll
        for (int half = 0; half < 2; ++half) {
#pragma unroll
            for (int sub = 0; sub < 2; ++sub) {
                const int base = sub*8;
                unsigned wa, wb, wc2, wd;
                float p0 = half ? s1[base+0] : s0[base+0];
                float p1 = half ? s1[base+1] : s0[base+1];
                float p2 = half ? s1[base+2] : s0[base+2];
                float p3 = half ? s1[base+3] : s0[base+3];
                float p4 = half ? s1[base+4] : s0[base+4];
                float p5 = half ? s1[base+5] : s0[base+5];
                float p6 = half ? s1[base+6] : s0[base+6];
                float p7 = half ? s1[base+7] : s0[base+7];
                asm("v_cvt_pk_bf16_f32 %0, %1, %2" : "=v"(wa) : "v"(p0), "v"(p1));
                asm("v_cvt_pk_bf16_f32 %0, %1, %2" : "=v"(wb) : "v"(p4), "v"(p5));
                asm("v_cvt_pk_bf16_f32 %0, %1, %2" : "=v"(wc2) : "v"(p2), "v"(p3));
                asm("v_cvt_pk_bf16_f32 %0, %1, %2" : "=v"(wd) : "v"(p6), "v"(p7));
                asm volatile("v_permlane32_swap_b32 %0, %1" : "+v"(wa), "+v"(wb));
                asm volatile("v_permlane32_swap_b32 %0, %1" : "+v"(wc2), "+v"(wd));
                u32x4 pu; pu[0] = wa; pu[1] = wc2; pu[2] = wb; pu[3] = wd;
                bf16x8 pa = __builtin_bit_cast(bf16x8, pu);
                const int ks = half*2 + sub;
                const int slot = ((ks*2 + hi) ^ (q31 & 7)) << 3;
                bf16x8 vf0 = *(const bf16x8*)(&Vs[cur][ q31     *64 + slot]);
                bf16x8 vf1 = *(const bf16x8*)(&Vs[cur][(32+q31)*64 + slot]);
                z0 = __builtin_amdgcn_mfma_f32_32x32x16_bf16(pa, vf0, z0, 0, 0, 0);
                z1 = __builtin_amdgcn_mfma_f32_32x32x16_bf16(pa, vf1, z1, 0, 0, 0);
            }
        }
        __builtin_amdgcn_s_setprio(0);

        mw = mwn;
    }

    Sc[w*32 + q31] = l_r;
    unsigned short* Zb = Z + ((size_t)(b*LSEQ + qw))*DMODEL + h*DKK + q31;
#pragma unroll
    for (int r = 0; r < 16; ++r) {
        const int row = (r & 3) + 8*(r >> 2) + 4*hi;
        const float rl = 1.0f / Sc[w*32 + row];
        Zb[(size_t)row*DMODEL]      = f2bf(z0[r] * rl);
        Zb[(size_t)row*DMODEL + 32] = f2bf(z1[r] * rl);
    }
}

// ---------------- LayerNorm (f32 in -> bf16 out) ----------------
__global__ __launch_bounds__(256) void ln_k(const float* __restrict__ r,
                                            const float* __restrict__ gam,
                                            const float* __restrict__ bet,
                                            unsigned short* __restrict__ out)
{
    const int row = blockIdx.x;
    const int t = threadIdx.x;
    const float* rp = r + (size_t)row * DMODEL;
    float4 v = *(const float4*)(rp + t*4);
    float s  = v.x + v.y + v.z + v.w;
    float s2 = v.x*v.x + v.y*v.y + v.z*v.z + v.w*v.w;
#pragma unroll
    for (int off = 32; off >= 1; off >>= 1) {
        s  += __shfl_xor(s,  off);
        s2 += __shfl_xor(s2, off);
    }
    __shared__ float red[8];
    const int wv = t >> 6;
    if ((t & 63) == 0) { red[wv] = s; red[4 + wv] = s2; }
    __syncthreads();
    s  = red[0] + red[1] + red[2] + red[3];
    s2 = red[4] + red[5] + red[6] + red[7];
    const float mu   = s  * (1.f/DMODEL);
    const float var  = s2 * (1.f/DMODEL) - mu*mu;
    const float rstd = rsqrtf(var + 1e-5f);
    float4 gv = *(const float4*)(gam + t*4);
    float4 bv = *(const float4*)(bet + t*4);
    ushort4 o;
    o.x = f2bf((v.x - mu)*rstd*gv.x + bv.x);
    o.y = f2bf((v.y - mu)*rstd*gv.y + bv.y);
    o.z = f2bf((v.z - mu)*rstd*gv.z + bv.z);
    o.w = f2bf((v.w - mu)*rstd*gv.w + bv.w);
    *(ushort4*)(out + (size_t)row * DMODEL + t*4) = o;
}

extern "C" void kernel_launch(void* const* d_in, const int* in_sizes, int n_in,
                              void* d_out, int out_size, void* d_ws, size_t ws_size,
                              hipStream_t stream)
{
    const float* x    = (const float*)d_in[0];
    const int*   mask = (const int*)  d_in[1];
    const float* WQ_w = (const float*)d_in[2];
    const float* WQ_b = (const float*)d_in[3];
    const float* WK_w = (const float*)d_in[4];
    const float* WK_b = (const float*)d_in[5];
    const float* WV_w = (const float*)d_in[6];
    const float* WV_b = (const float*)d_in[7];
    const float* WO_w = (const float*)d_in[8];
    const float* WO_b = (const float*)d_in[9];
    const float* ln_g = (const float*)d_in[10];
    const float* ln_b = (const float*)d_in[11];
    const float* W1_w = (const float*)d_in[12];
    const float* W1_b = (const float*)d_in[13];
    const float* W2_w = (const float*)d_in[14];
    const float* W2_b = (const float*)d_in[15];
    float* out = (float*)d_out;

    char* w = (char*)d_ws;
    const size_t MB = 1024*1024;
    unsigned short* qk   = (unsigned short*)(w + 0*MB);    // 32MB  Q|K rowmajor
    unsigned short* vtb  = (unsigned short*)(w + 32*MB);   // 32MB  V^T
    unsigned short* shr  = (unsigned short*)(w + 64*MB);   // 16MB  xb / Zb / hln / P0
    float*          rb   = (float*)         (w + 80*MB);   // 32MB  (bqkv early)
    unsigned short* wqkv = (unsigned short*)(w + 112*MB);  // 6MB   (P1 later)
    unsigned short* wob  = (unsigned short*)(w + 118*MB);  // 2MB
    unsigned short* w1b  = (unsigned short*)(w + 120*MB);  // 8MB
    unsigned short* w2b  = (unsigned short*)(w + 128*MB);  // 8MB
    unsigned long long* mbits = (unsigned long long*)(w + 136*MB); // 2MB -> 138MB
    float* bqkv = (float*)rb;                              // dead before WO writes rb
    unsigned short* xb   = shr;
    unsigned short* Zb   = shr;
    unsigned short* hln  = shr;
    unsigned short* hmid = (unsigned short*)(w + 0*MB);    // qk+vtb dead after attn
    unsigned short* P0   = shr;                            // hln dead after W1
    unsigned short* P1   = wqkv;                           // weights dead after W1

    // fused casts (weights + x + biases) + bitmask
    cast_weights_k<<<2048, 256, 0, stream>>>(WQ_w, WK_w, WV_w, WO_w, W1_w, W2_w, x,
                                             wqkv, wob, w1b, w2b, xb,
                                             WQ_b, WK_b, WV_b, bqkv);
    maskbits_k<<<65536, 256, 0, stream>>>(mask, mbits);

    // fused QKV projection on 8-phase 256x256 (MODE 3: QK rowmajor + V^T)
    gemm8<3, 16><<<dim3(384), dim3(512), 0, stream>>>(xb, wqkv, bqkv, nullptr, qk, vtb,
                                                      MROWS, 3072, DMODEL, 0.18033688f);
    // fused attention
    attn_k<<<dim3(1024), dim3(256), 0, stream>>>(qk, vtb, mbits, Zb);
    // WO projection + residual 1 -> r (f32); 2-phase 256x128, grid 256
    gemm8n<2, 16><<<dim3(256), dim3(512), 0, stream>>>(Zb, wob, WO_b, x, rb,
                                                       MROWS, DMODEL, DMODEL);
    // pre-LN of FFN
    ln_k<<<MROWS, 256, 0, stream>>>(rb, ln_g, ln_b, hln);
    // FFN
    gemm8<1, 16><<<dim3(512), dim3(512), 0, stream>>>(hln, w1b, W1_b, nullptr, hmid, nullptr,
                                                      MROWS, DFFN, DMODEL, 1.0f);
    // W2 split-K=2: 256 blocks (full machine), bf16 partials P0/P1
    gemm8<4, 32><<<dim3(256), dim3(512), 0, stream>>>(hmid, w2b, nullptr, nullptr, P0, P1,
                                                      MROWS, DMODEL, DFFN, 1.0f);
    // final reduce: out = rb + b2 + P0 + P1
    reduce2_k<<<2048, 256, 0, stream>>>(P0, P1, rb, W2_b, out);
}